// Round 7
// baseline (242.515 us; speedup 1.0000x reference)
//
#include <hip/hip_runtime.h>

#define SCALE   0.25f
#define NBATCH  8
#define CCH     256
#define HH      128
#define WW      128
#define HW      (HH * WW)
#define NBUCK   (NBATCH * HH)   // 1024 buckets = (batch, y_low)
#define CAP     160             // slots per bucket (mean 97.7, sd 9.9)

#define CG      32              // channels per k_main block
#define NCG     (CCH / CG)      // 8

typedef float f32x4 __attribute__((ext_vector_type(4)));  // native vec for nontemporal builtin

// ws layout: [0, 4096) cnt (1024 ints) | [4096, ...) slots: int4[NBUCK*CAP] = 2.62 MB
// record = {p, xlo|xhi<<8|(!valid)<<31, bits(lx), bits(ly)}

// 391 blocks x 256 threads (full CU coverage). LDS histogram gives local
// positions; ONE global atomic per (block,bucket) reserves the range.
__global__ __launch_bounds__(256) void k_bin(
    const float* __restrict__ rois, int* __restrict__ cnt,
    int4* __restrict__ slots, int P)
{
    __shared__ int lhist[NBUCK];
    __shared__ int lbase[NBUCK];
    const int t = threadIdx.x;
    for (int k = t; k < NBUCK; k += 256) lhist[k] = 0;
    __syncthreads();

    int p = blockIdx.x * 256 + t;
    int mybk = -1, mypos = 0;
    int4 myrec = make_int4(0, 0, 0, 0);
    if (p < P) {
        float fb = rois[3 * p];
        float fx = rois[3 * p + 1] * SCALE;
        float fy = rois[3 * p + 2] * SCALE;
        int b = (int)fb;
        bool valid = (fy >= -1.0f) && (fy <= (float)HH) &&
                     (fx >= -1.0f) && (fx <= (float)WW);
        float y = fmaxf(fy, 0.0f);
        float x = fmaxf(fx, 0.0f);
        int ylo = (int)floorf(y);
        int xlo = (int)floorf(x);
        float yf = y, xf = x;
        int xhi;
        if (ylo >= HH - 1) { ylo = HH - 1; yf = (float)ylo; }
        if (xlo >= WW - 1) { xlo = WW - 1; xhi = WW - 1; xf = (float)xlo; }
        else               { xhi = xlo + 1; }
        float ly = yf - (float)ylo;
        float lx = xf - (float)xlo;
        unsigned pk = (unsigned)xlo | ((unsigned)xhi << 8) | (valid ? 0u : 0x80000000u);
        int bk = b * HH + ylo;
        mybk  = bk;
        mypos = atomicAdd(&lhist[bk], 1);   // LDS atomic
        myrec = make_int4(p, (int)pk, __float_as_int(lx), __float_as_int(ly));
    }
    __syncthreads();
    for (int k = t; k < NBUCK; k += 256) {
        int h = lhist[k];
        lbase[k] = h ? atomicAdd(&cnt[k], h) : 0;
    }
    __syncthreads();
    if (mybk >= 0) {
        int idx = lbase[mybk] + mypos;
        if (idx < CAP) slots[mybk * CAP + idx] = myrec;
    }
}

// One block (512 thr, 48 KB LDS) per (bucket-PAIR, 32-channel group):
// stages rows y0,y0+1,y0+2 — the middle row is shared by both buckets
// (halo amortized: staged fetch 268 -> 201 MB) and serves ~196 records.
// 4096 blocks, 3 resident/CU = 6 bucket-units in flight per CU (vs 4):
// round-6 post-mortem says k_main is latency-round-bound (8 rounds of
// full stage-chain latency); this cuts rounds to ~5.3 and overlaps more.
// LDS transposed: float4 lds4[row 3][x 128][slot 8], slot=(cq+(x>>2))&7 ->
// ds_read_b128 gathers and ds_write_b128 staging both ~uniform-bank (free).
// Records prefetched 3 batches deep BEFORE the staging loads (parallel
// latency). Stores: 128 B contiguous nontemporal per record (full L2 line;
// write-once data bypasses cache, keeping L2/L3 for feature rows).
__global__ __launch_bounds__(512, 6) void k_main(
    const float* __restrict__ feat, const int4* __restrict__ slots,
    const int* __restrict__ cnt_arr, float* __restrict__ out)
{
    const int bkp = blockIdx.x & 511;          // bucket-pair id (fast -> XCD spread)
    const int cgp = blockIdx.x >> 9;           // channel group 0..7
    const int b   = bkp >> 6;
    const int y0  = (bkp & 63) * 2;
    const int bk0 = b * HH + y0;

    const int n0 = min(cnt_arr[bk0], CAP);
    const int n1 = min(cnt_arr[bk0 + 1], CAP);
    const int tot = n0 + n1;
    if (tot == 0) return;

    __shared__ __align__(16) float4 lds4[3][WW][8];   // 48 KB

    const int t    = threadIdx.x;
    const int wv   = t >> 6;            // 0..7
    const int lane = t & 63;
    const int sub  = lane >> 3;         // 0..7: record slot within wave-iter
    const int cq   = lane & 7;          // channel quad 0..7

    // ---- record prefetch FIRST (L2 latency runs parallel to staging)
    const int4* sb = slots + (size_t)bk0 * CAP;
    const int ii0 = wv * 8;
    int j0 = min(ii0 + sub, tot - 1);        int q0 = j0 >= n0;
    int j1 = min(ii0 + 64 + sub, tot - 1);   int q1 = j1 >= n0;
    int j2 = min(ii0 + 128 + sub, tot - 1);  int q2 = j2 >= n0;
    int4 rc0 = sb[q0 ? CAP + j0 - n0 : j0];
    int4 rc1 = sb[q1 ? CAP + j1 - n0 : j1];
    int4 rc2 = sb[q2 ? CAP + j2 - n0 : j2];

    // ---- staging: 3 rows x 32 ch x 128 x = 48 KB, transposed.
    // 768 units (row, cq8, xq); each = 4ch x 4x: 4 float4 loads, 4 b128 writes.
    for (int u = t; u < 768; u += 512) {
        const int xq  = u & 31;
        const int cq8 = (u >> 5) & 7;
        const int row = u >> 8;          // 0..2
        const int y   = min(y0 + row, HH - 1);
        const float* g = feat + ((size_t)(b * CCH + cgp * CG + 4 * cq8) * HH + y) * WW + 4 * xq;
        float4 f0 = *(const float4*)(g);
        float4 f1 = *(const float4*)(g + HW);
        float4 f2 = *(const float4*)(g + 2 * HW);
        float4 f3 = *(const float4*)(g + 3 * HW);
        float4* d = &lds4[row][4 * xq][(cq8 + xq) & 7];
        d[0]  = make_float4(f0.x, f1.x, f2.x, f3.x);   // x = 4xq+0
        d[8]  = make_float4(f0.y, f1.y, f2.y, f3.y);   // x = 4xq+1
        d[16] = make_float4(f0.z, f1.z, f2.z, f3.z);
        d[24] = make_float4(f0.w, f1.w, f2.w, f3.w);
    }
    __syncthreads();

    float* const outbase = out + cgp * CG + 4 * cq;

    auto process = [&](int4 r, int q, bool act) {
        unsigned pk = (unsigned)r.y;
        float lx = __int_as_float(r.z);
        float ly = __int_as_float(r.w);
        float s  = ((int)pk < 0) ? 0.0f : 1.0f;   // validity mask
        float hy  = (1.0f - ly) * s;
        float lys = ly * s;
        float hx  = 1.0f - lx;
        float w1 = hy * hx, w2 = hy * lx, w3 = lys * hx, w4 = lys * lx;
        int xlo = pk & 255;
        int xhi = (pk >> 8) & 255;
        int alo = xlo * 8 + ((cq + (xlo >> 2)) & 7);
        int ahi = xhi * 8 + ((cq + (xhi >> 2)) & 7);
        const float4* lo = &lds4[q][0][0];       // bucket q: rows q, q+1
        const float4* hi = lo + WW * 8;
        float4 v1 = lo[alo], v2 = lo[ahi];
        float4 v3 = hi[alo], v4 = hi[ahi];
        f32x4 o;
        o.x = w1 * v1.x + w2 * v2.x + w3 * v3.x + w4 * v4.x;
        o.y = w1 * v1.y + w2 * v2.y + w3 * v3.y + w4 * v4.y;
        o.z = w1 * v1.z + w2 * v2.z + w3 * v3.z + w4 * v4.z;
        o.w = w1 * v1.w + w2 * v2.w + w3 * v3.w + w4 * v4.w;
        if (act)
            __builtin_nontemporal_store(o, (f32x4*)(outbase + (size_t)r.x * CCH));
    };

    process(rc0, q0, ii0 + sub < tot);
    if (ii0 + 64 < tot)  process(rc1, q1, ii0 + 64 + sub < tot);
    if (ii0 + 128 < tot) process(rc2, q2, ii0 + 128 + sub < tot);
    for (int ii = ii0 + 192; ii < tot; ii += 64) {        // rare tail
        int j = min(ii + sub, tot - 1);
        int q = j >= n0;
        process(sb[q ? CAP + j - n0 : j], q, ii + sub < tot);
    }
}

extern "C" void kernel_launch(void* const* d_in, const int* in_sizes, int n_in,
                              void* d_out, int out_size, void* d_ws, size_t ws_size,
                              hipStream_t stream) {
    const float* feat = (const float*)d_in[0];   // (8,256,128,128) fp32
    const float* rois = (const float*)d_in[1];   // (P,3) fp32
    float* out = (float*)d_out;                  // (P,256) fp32
    const int P = in_sizes[1] / 3;

    int*  cnt   = (int*)d_ws;
    int4* slots = (int4*)((char*)d_ws + NBUCK * sizeof(int));

    hipMemsetAsync(cnt, 0, NBUCK * sizeof(int), stream);
    const int bb = (P + 255) / 256;              // 391 blocks
    k_bin<<<bb, 256, 0, stream>>>(rois, cnt, slots, P);
    k_main<<<NCG * NBATCH * (HH / 2), 512, 0, stream>>>(feat, slots, cnt, out);
}